// Round 6
// baseline (6109.495 us; speedup 1.0000x reference)
//
#include <hip/hip_runtime.h>
#include <hip/hip_bf16.h>
#include <math.h>
#include <cstddef>

namespace {

constexpr int kB   = 128;
constexpr int kS   = 256;
constexpr int kD   = 768;
constexpr int kSP  = 257;
constexpr int kN   = kB * kSP;   // 32896
constexpr int kARC = 500;
constexpr int kTAG = 100;

// ---------- per-tensor dtype detection (1 = bf16 storage, 0 = fp32) ----------
__global__ void detect_dtype_n(const unsigned* __restrict__ raw, int* __restrict__ flag,
                               int nwords) {
  int lane = threadIdx.x;  // 64
  int ok = 0, nz = 0;
  if (lane < nwords) {
    unsigned w = raw[lane];
    if (w != 0u) {
      nz = 1;
      int e = (w >> 7) & 0xFF;
      ok = (e >= 90 && e <= 140);
    }
  }
  unsigned long long ball_ok = __ballot(ok);
  unsigned long long ball_nz = __ballot(nz);
  if (lane == 0) {
    int cok = __popcll(ball_ok), cnz = __popcll(ball_nz);
    flag[0] = (cok * 4 >= cnz * 3) ? 1 : 0;   // all-zero => bf16 path (safe either way)
  }
}

__device__ __forceinline__ float rawload(const void* p, size_t i, int bf) {
  return bf ? __bfloat162float(((const __hip_bfloat16*)p)[i]) : ((const float*)p)[i];
}

__global__ void conv_to_f32(const void* __restrict__ src, float* __restrict__ dst,
                            int n, const int* __restrict__ flag) {
  int i = blockIdx.x * 256 + threadIdx.x;
  if (i >= n) return;
  dst[i] = rawload(src, i, *flag);
}

// ---- projection GEMM: C[NG,M] = elu( X[NG,768] @ W[768,M] + bias ) ----
// X virtual: row -> (r==0 ? sentinel : inputs[g0+b_loc, r-1, :])
__global__ __launch_bounds__(256) void proj_gemm(
    const void* __restrict__ inp, const void* __restrict__ sent,
    const int* __restrict__ flag_inp, const int* __restrict__ flag_sent,
    const float* __restrict__ W, const float* __restrict__ bias,
    float* __restrict__ C, int NG, int M, int g0) {
  __shared__ float As[16][68];
  __shared__ float Bs[16][68];
  const int bf_i = *flag_inp;
  const int bf_s = *flag_sent;
  const int tid = threadIdx.x;
  const int tx = tid & 15, ty = tid >> 4;
  const int n0 = blockIdx.x * 64, m0 = blockIdx.y * 64;
  const int a_nn = tid >> 2, a_kk = (tid & 3) * 4;
  const int b_kk = tid >> 4, b_mm = (tid & 15) * 4;
  float acc[4][4] = {};
  for (int k0 = 0; k0 < kD; k0 += 16) {
    {
      const int r_loc = n0 + a_nn;
      float v[4] = {0.f, 0.f, 0.f, 0.f};
      if (r_loc < NG) {
        const int b_loc = r_loc / kSP;
        const int r = r_loc - b_loc * kSP;
        const int k = k0 + a_kk;
        if (r == 0) {
#pragma unroll
          for (int q = 0; q < 4; ++q) v[q] = rawload(sent, k + q, bf_s);
        } else {
          const size_t base = ((size_t)((g0 + b_loc) * kS + (r - 1))) * kD;
#pragma unroll
          for (int q = 0; q < 4; ++q) v[q] = rawload(inp, base + k + q, bf_i);
        }
      }
#pragma unroll
      for (int q = 0; q < 4; ++q) As[a_kk + q][a_nn] = v[q];
    }
    {
      const int k = k0 + b_kk;
      const int m = m0 + b_mm;
      float v[4];
#pragma unroll
      for (int q = 0; q < 4; ++q) {
        int mm = m + q;
        v[q] = (mm < M) ? W[(size_t)k * M + mm] : 0.f;
      }
#pragma unroll
      for (int q = 0; q < 4; ++q) Bs[b_kk][b_mm + q] = v[q];
    }
    __syncthreads();
#pragma unroll
    for (int kk = 0; kk < 16; ++kk) {
      float av[4], bv[4];
#pragma unroll
      for (int i = 0; i < 4; ++i) av[i] = As[kk][ty * 4 + i];
#pragma unroll
      for (int j = 0; j < 4; ++j) bv[j] = Bs[kk][tx * 4 + j];
#pragma unroll
      for (int i = 0; i < 4; ++i)
#pragma unroll
        for (int j = 0; j < 4; ++j) acc[i][j] += av[i] * bv[j];
    }
    __syncthreads();
  }
#pragma unroll
  for (int i = 0; i < 4; ++i) {
    const int n = n0 + ty * 4 + i;
    if (n >= NG) continue;
#pragma unroll
    for (int j = 0; j < 4; ++j) {
      const int m = m0 + tx * 4 + j;
      if (m >= M) continue;
      float v = acc[i][j] + bias[m];
      v = v > 0.f ? v : expm1f(v);
      C[(size_t)n * M + m] = v;
    }
  }
}

// ------------- tiled fp32 GEMM: C = A@B (+bias_row) -------------
__global__ __launch_bounds__(256) void gemm_nn(
    const float* __restrict__ A, int lda,
    const float* __restrict__ Bm, int ldb,
    float* __restrict__ C, int ldc,
    int Nr, int K, int M,
    const float* __restrict__ bias_row) {
  __shared__ float As[16][68];
  __shared__ float Bs[16][68];
  const int tid = threadIdx.x;
  const int tx = tid & 15, ty = tid >> 4;
  const int n0 = blockIdx.x * 64, m0 = blockIdx.y * 64;
  const int a_nn = tid >> 2, a_kk = (tid & 3) * 4;
  const int b_kk = tid >> 4, b_mm = (tid & 15) * 4;
  float acc[4][4] = {};
  for (int k0 = 0; k0 < K; k0 += 16) {
    {
      const int n = n0 + a_nn;
      float v[4];
      if (n < Nr && (k0 + a_kk + 3) < K) {
        const float* p = A + (size_t)n * lda + (k0 + a_kk);
        v[0] = p[0]; v[1] = p[1]; v[2] = p[2]; v[3] = p[3];
      } else {
#pragma unroll
        for (int q = 0; q < 4; ++q) {
          int k = k0 + a_kk + q;
          v[q] = (n < Nr && k < K) ? A[(size_t)n * lda + k] : 0.f;
        }
      }
#pragma unroll
      for (int q = 0; q < 4; ++q) As[a_kk + q][a_nn] = v[q];
    }
    {
      const int k = k0 + b_kk;
      const int m = m0 + b_mm;
      float v[4];
      if (k < K && (m + 3) < M) {
        const float* p = Bm + (size_t)k * ldb + m;
        v[0] = p[0]; v[1] = p[1]; v[2] = p[2]; v[3] = p[3];
      } else {
#pragma unroll
        for (int q = 0; q < 4; ++q) {
          int mm = m + q;
          v[q] = (k < K && mm < M) ? Bm[(size_t)k * ldb + mm] : 0.f;
        }
      }
#pragma unroll
      for (int q = 0; q < 4; ++q) Bs[b_kk][b_mm + q] = v[q];
    }
    __syncthreads();
#pragma unroll
    for (int kk = 0; kk < 16; ++kk) {
      float av[4], bv[4];
#pragma unroll
      for (int i = 0; i < 4; ++i) av[i] = As[kk][ty * 4 + i];
#pragma unroll
      for (int j = 0; j < 4; ++j) bv[j] = Bs[kk][tx * 4 + j];
#pragma unroll
      for (int i = 0; i < 4; ++i)
#pragma unroll
        for (int j = 0; j < 4; ++j) acc[i][j] += av[i] * bv[j];
    }
    __syncthreads();
  }
#pragma unroll
  for (int i = 0; i < 4; ++i) {
    const int n = n0 + ty * 4 + i;
    if (n >= Nr) continue;
#pragma unroll
    for (int j = 0; j < 4; ++j) {
      const int m = m0 + tx * 4 + j;
      if (m >= M) continue;
      float v = acc[i][j];
      if (bias_row) v += bias_row[m];
      C[(size_t)n * ldc + m] = v;
    }
  }
}

// --- batched NT bilinear: out[b,i,j] = sum_e T[b,i,e]*Dp[b,j,e] + T[b,i,500] + bil_b ---
// GLOB=1: write to global fp32 out at batch (g0+b); GLOB=0: local batch b.
template <int GLOB>
__global__ __launch_bounds__(256) void bil_nt(
    const float* __restrict__ T,   // [GB,257,501]
    const float* __restrict__ Dp,  // [GB,257,500]
    float* __restrict__ Cf,
    const float* __restrict__ bilb, int bidx, int g0) {
  __shared__ float As[16][68];
  __shared__ float Bs[16][68];
  const int b = blockIdx.z;
  const int i0 = blockIdx.x * 64, j0 = blockIdx.y * 64;
  const int tid = threadIdx.x;
  const int tx = tid & 15, ty = tid >> 4;
  const int r_ii = tid >> 2, r_ee = (tid & 3) * 4;
  const float* Tb = T + (size_t)b * kSP * 501;
  const float* Db = Dp + (size_t)b * kSP * 500;
  float acc[4][4] = {};
  for (int e0 = 0; e0 < 500; e0 += 16) {
    {
      const int i = i0 + r_ii;
      float v[4];
#pragma unroll
      for (int q = 0; q < 4; ++q) {
        int e = e0 + r_ee + q;
        v[q] = (i < kSP && e < 500) ? Tb[(size_t)i * 501 + e] : 0.f;
      }
#pragma unroll
      for (int q = 0; q < 4; ++q) As[r_ee + q][r_ii] = v[q];
    }
    {
      const int j = j0 + r_ii;
      float v[4];
#pragma unroll
      for (int q = 0; q < 4; ++q) {
        int e = e0 + r_ee + q;
        v[q] = (j < kSP && e < 500) ? Db[(size_t)j * 500 + e] : 0.f;
      }
#pragma unroll
      for (int q = 0; q < 4; ++q) Bs[r_ee + q][r_ii] = v[q];
    }
    __syncthreads();
#pragma unroll
    for (int kk = 0; kk < 16; ++kk) {
      float av[4], bv[4];
#pragma unroll
      for (int i = 0; i < 4; ++i) av[i] = As[kk][ty * 4 + i];
#pragma unroll
      for (int j = 0; j < 4; ++j) bv[j] = Bs[kk][tx * 4 + j];
#pragma unroll
      for (int i = 0; i < 4; ++i)
#pragma unroll
        for (int j = 0; j < 4; ++j) acc[i][j] += av[i] * bv[j];
    }
    __syncthreads();
  }
  const float sb = bilb[bidx];
#pragma unroll
  for (int ii = 0; ii < 4; ++ii) {
    const int i = i0 + ty * 4 + ii;
    if (i >= kSP) continue;
    const float tr = Tb[(size_t)i * 501 + 500] + sb;
#pragma unroll
    for (int jj = 0; jj < 4; ++jj) {
      const int j = j0 + tx * 4 + jj;
      if (j >= kSP) continue;
      const int bb = GLOB ? (g0 + b) : b;
      Cf[((size_t)bb * kSP + i) * kSP + j] = acc[ii][jj] + tr;
    }
  }
}

// ------------- per-row softmax + top-8 (+dinv); one wave per row -------------
__global__ void softmax_topk(const float* __restrict__ logits,
                             int* __restrict__ idx8,
                             float* __restrict__ val8,
                             float* __restrict__ dinv) {
  const int row = blockIdx.x;
  const int lane = threadIdx.x;  // 64
  const int rowbase = row - (row % kSP);
  const float* L = logits + (size_t)row * kSP;
  float v[5];
  int c[5];
#pragma unroll
  for (int q = 0; q < 5; ++q) {
    int j = lane + q * 64;
    c[q] = j;
    v[q] = (j < kSP) ? L[j] : -INFINITY;
  }
  float m = v[0];
#pragma unroll
  for (int q = 1; q < 5; ++q) m = fmaxf(m, v[q]);
  for (int off = 32; off > 0; off >>= 1) m = fmaxf(m, __shfl_xor(m, off));
  float s = 0.f;
#pragma unroll
  for (int q = 0; q < 5; ++q) s += expf(v[q] - m);
  for (int off = 32; off > 0; off >>= 1) s += __shfl_xor(s, off);
  const float invs = 1.f / s;
  float degsum = 0.f;
  for (int t = 0; t < 8; ++t) {
    float bvv = -INFINITY;
    int bii = kSP;
#pragma unroll
    for (int q = 0; q < 5; ++q)
      if (v[q] > bvv) { bvv = v[q]; bii = c[q]; }
    for (int off = 32; off > 0; off >>= 1) {
      float ov = __shfl_xor(bvv, off);
      int oi = __shfl_xor(bii, off);
      if (ov > bvv || (ov == bvv && oi < bii)) { bvv = ov; bii = oi; }
    }
    float p = expf(bvv - m) * invs;
    degsum += p;
    if (lane == 0) { idx8[row * 8 + t] = rowbase + bii; val8[row * 8 + t] = p; }
#pragma unroll
    for (int q = 0; q < 5; ++q)
      if (c[q] == bii) v[q] = -INFINITY;
  }
  if (lane == 0) dinv[row] = 1.f / sqrtf(1.f + degsum);
}

// ------------- GCN aggregation -------------
template <int ELU>
__global__ __launch_bounds__(256) void gcn_agg(
    const float* __restrict__ Y, int F,
    const int* __restrict__ idx8, const float* __restrict__ val8,
    const float* __restrict__ dinv,
    const float* __restrict__ bias,
    float* __restrict__ outF) {
  const int n = blockIdx.x;
  __shared__ float w[9];
  __shared__ int srcs[8];
  const int t = threadIdx.x;
  if (t < 8) {
    int s = idx8[n * 8 + t];
    srcs[t] = s;
    w[t] = dinv[n] * val8[n * 8 + t] * dinv[s];
  } else if (t == 8) {
    float di = dinv[n];
    w[8] = di * di;
  }
  __syncthreads();
  for (int f = t; f < F; f += blockDim.x) {
    float acc = w[8] * Y[(size_t)n * F + f];
#pragma unroll
    for (int k = 0; k < 8; ++k) acc += w[k] * Y[(size_t)srcs[k] * F + f];
    acc += bias[f];
    if (ELU) acc = acc > 0.f ? acc : expm1f(acc);
    outF[(size_t)n * F + f] = acc;
  }
}

__global__ void copy_f32(const float* __restrict__ in, float* __restrict__ out, int n) {
  int i = blockIdx.x * 256 + threadIdx.x;
  if (i < n) out[i] = in[i];
}

}  // namespace

extern "C" void kernel_launch(void* const* d_in, const int* in_sizes, int n_in,
                              void* d_out, int out_size, void* d_ws, size_t ws_size,
                              hipStream_t stream) {
  (void)out_size;

  // ---------- size-keyed role mapping ----------
  const int roleSize[20] = {kB * kS * kD, kD,
                            kD * kARC, kARC, kD * kARC, kARC,
                            kD * kTAG, kTAG, kD * kTAG, kTAG,
                            3 * 501 * 501, 3,
                            kARC * kARC, kARC, kARC * kARC, kARC,
                            kTAG * kTAG, kTAG, kTAG * kTAG, kTAG};
  const int roleOcc[20]  = {0, 0, 0, 0, 1, 1, 0, 0, 1, 1, 0, 0,
                            0, 2, 1, 3, 0, 2, 1, 3};
  int roleIdx[20] = {0, 5, 6, 7, 8, 9, 10, 11, 12, 13, 14, 15,
                     16, 17, 18, 19, 20, 21, 22, 23};
  for (int r = 0; r < 20; ++r) {
    int occ = 0, found = -1;
    for (int i = 0; i < n_in; ++i) {
      if (in_sizes[i] == roleSize[r]) {
        if (occ == roleOcc[r]) { found = i; break; }
        ++occ;
      }
    }
    if (found >= 0) roleIdx[r] = found;
    else if (roleIdx[r] >= n_in) roleIdx[r] = 0;
  }
  const void* src_of[20];
  for (int r = 0; r < 20; ++r) src_of[r] = d_in[roleIdx[r]];

  // ---- group size so the layout fits ws_size ----
  auto need_bytes = [](int GB) -> size_t {
    size_t NG = (size_t)GB * kSP, s = 0;
    auto al = [&](size_t b) { s += (b + 255) & ~(size_t)255; };
    al(256);
    al((size_t)kD * kARC * 4); al(kARC * 4);
    al((size_t)kD * kARC * 4); al(kARC * 4);
    al((size_t)kD * kTAG * 4); al(kTAG * 4);
    al((size_t)kD * kTAG * 4); al(kTAG * 4);
    al((size_t)3 * 501 * 501 * 4); al(3 * 4);
    al((size_t)kARC * kARC * 4); al(kARC * 4);
    al((size_t)kARC * kARC * 4); al(kARC * 4);
    al((size_t)kTAG * kTAG * 4); al(kTAG * 4);
    al((size_t)kTAG * kTAG * 4); al(kTAG * 4);
    al(NG * kARC * 4); al(NG * kARC * 4);
    al(NG * kTAG * 4); al(NG * kTAG * 4);
    al(NG * 501 * 4);
    al(NG * kARC * 4);
    al(NG * 8 * 4); al(NG * 8 * 4); al(NG * 4);
    return s;
  };
  int GB = 1;
  for (int cand : {128, 64, 32, 16, 8, 4, 2, 1}) {
    if (need_bytes(cand) <= ws_size) { GB = cand; break; }
  }
  const int G = kB / GB;
  const int NG = GB * kSP;

  char* ws = (char*)d_ws;
  size_t off = 0;
  auto alloc = [&](size_t bytes) -> void* {
    void* p = ws + off;
    off += (bytes + 255) & ~(size_t)255;
    return p;
  };
  int*   flags = (int*)alloc(256);
  float* W_ha = (float*)alloc((size_t)kD * kARC * 4);
  float* b_ha = (float*)alloc(kARC * 4);
  float* W_da = (float*)alloc((size_t)kD * kARC * 4);
  float* b_da = (float*)alloc(kARC * 4);
  float* W_ht = (float*)alloc((size_t)kD * kTAG * 4);
  float* b_ht = (float*)alloc(kTAG * 4);
  float* W_dt = (float*)alloc((size_t)kD * kTAG * 4);
  float* b_dt = (float*)alloc(kTAG * 4);
  float* bilW = (float*)alloc((size_t)3 * 501 * 501 * 4);
  float* bilb = (float*)alloc(3 * 4);
  float* c1aW = (float*)alloc((size_t)kARC * kARC * 4);
  float* c1ab = (float*)alloc(kARC * 4);
  float* c2aW = (float*)alloc((size_t)kARC * kARC * 4);
  float* c2ab = (float*)alloc(kARC * 4);
  float* c1rW = (float*)alloc((size_t)kTAG * kTAG * 4);
  float* c1rb = (float*)alloc(kTAG * 4);
  float* c2rW = (float*)alloc((size_t)kTAG * kTAG * 4);
  float* c2rb = (float*)alloc(kTAG * 4);
  float* featHA = (float*)alloc((size_t)NG * kARC * 4);
  float* featDA = (float*)alloc((size_t)NG * kARC * 4);
  float* featHT = (float*)alloc((size_t)NG * kTAG * 4);
  float* featDT = (float*)alloc((size_t)NG * kTAG * 4);
  float* Y    = (float*)alloc((size_t)NG * 501 * 4);
  float* Z    = (float*)alloc((size_t)NG * kARC * 4);
  int*   idx8 = (int*)alloc((size_t)NG * 8 * 4);
  float* val8 = (float*)alloc((size_t)NG * 8 * 4);
  float* dinv = (float*)alloc((size_t)NG * 4);

  // 0) per-tensor dtype detection + fp32 canonicalization of params
  for (int r = 0; r < 20; ++r) {
    int n = roleSize[r];
    int nwords = n / 4; if (nwords < 1) nwords = 1; if (nwords > 64) nwords = 64;
    detect_dtype_n<<<1, 64, 0, stream>>>((const unsigned*)src_of[r], flags + r, nwords);
  }
  float* dst_of[20] = {nullptr, nullptr, W_ha, b_ha, W_da, b_da, W_ht, b_ht, W_dt, b_dt,
                       bilW, bilb, c1aW, c1ab, c2aW, c2ab, c1rW, c1rb, c2rW, c2rb};
  for (int r = 2; r < 20; ++r) {
    int n = roleSize[r];
    conv_to_f32<<<(n + 255) / 256, 256, 0, stream>>>(src_of[r], dst_of[r], n, flags + r);
  }

  float* outp = (float*)d_out;   // fp32 output! (reference returns float32)
  const size_t arc_elems = (size_t)kB * kSP * kSP;
  const int nb64 = (NG + 63) / 64;

  auto two_conv = [&](float* feat, int F,
                      const float* W1, const float* B1,
                      const float* W2, const float* B2) {
    dim3 gg(nb64, (F + 63) / 64);
    int ablk = (F <= 128) ? 128 : 256;
    gemm_nn<<<gg, 256, 0, stream>>>(feat, F, W1, F, Y, F, NG, F, F, nullptr);
    gcn_agg<1><<<NG, ablk, 0, stream>>>(Y, F, idx8, val8, dinv, B1, Z);
    gemm_nn<<<gg, 256, 0, stream>>>(Z, F, W2, F, Y, F, NG, F, F, nullptr);
    gcn_agg<0><<<NG, ablk, 0, stream>>>(Y, F, idx8, val8, dinv, B2, feat);
  };

  for (int g = 0; g < G; ++g) {
    const int g0 = g * GB;

    proj_gemm<<<dim3(nb64, 8), 256, 0, stream>>>(src_of[0], src_of[1], flags + 0, flags + 1,
                                                 W_ha, b_ha, featHA, NG, kARC, g0);
    proj_gemm<<<dim3(nb64, 8), 256, 0, stream>>>(src_of[0], src_of[1], flags + 0, flags + 1,
                                                 W_da, b_da, featDA, NG, kARC, g0);
    proj_gemm<<<dim3(nb64, 2), 256, 0, stream>>>(src_of[0], src_of[1], flags + 0, flags + 1,
                                                 W_ht, b_ht, featHT, NG, kTAG, g0);
    proj_gemm<<<dim3(nb64, 2), 256, 0, stream>>>(src_of[0], src_of[1], flags + 0, flags + 1,
                                                 W_dt, b_dt, featDT, NG, kTAG, g0);

    for (int k = 0; k < 2; ++k) {
      const float* Wk = bilW + (size_t)k * 501 * 501;
      // T = [featHA|1] @ Wk  -> Y [NG,501]
      gemm_nn<<<dim3(nb64, 8), 256, 0, stream>>>(featHA, kARC, Wk, 501, Y, 501,
                                                 NG, kARC, 501, Wk + (size_t)500 * 501);
      // logits = T @ [featDA|1]^T + bil_b -> Z (local)
      bil_nt<0><<<dim3(5, 5, GB), 256, 0, stream>>>(Y, featDA, Z, bilb, k, g0);
      softmax_topk<<<NG, 64, 0, stream>>>(Z, idx8, val8, dinv);
      two_conv(featHA, kARC, c1aW, c1ab, c2aW, c2ab);
      two_conv(featDA, kARC, c1aW, c1ab, c2aW, c2ab);
      two_conv(featHT, kTAG, c1rW, c1rb, c2rW, c2rb);
      two_conv(featDT, kTAG, c1rW, c1rb, c2rW, c2rb);
    }

    // final bilinear -> d_out (fp32), global batch offset g0
    const float* Wf = bilW + (size_t)2 * 501 * 501;
    gemm_nn<<<dim3(nb64, 8), 256, 0, stream>>>(featHA, kARC, Wf, 501, Y, 501,
                                               NG, kARC, 501, Wf + (size_t)500 * 501);
    bil_nt<1><<<dim3(5, 5, GB), 256, 0, stream>>>(Y, featDA, outp, bilb, 2, g0);

    // tag outputs (fp32)
    copy_f32<<<(NG * kTAG + 255) / 256, 256, 0, stream>>>(
        featHT, outp + arc_elems + (size_t)g0 * kSP * kTAG, NG * kTAG);
    copy_f32<<<(NG * kTAG + 255) / 256, 256, 0, stream>>>(
        featDT, outp + arc_elems + (size_t)kN * kTAG + (size_t)g0 * kSP * kTAG, NG * kTAG);
  }
}

// Round 7
// 3168.768 us; speedup vs baseline: 1.9280x; 1.9280x over previous
//
#include <hip/hip_runtime.h>
#include <hip/hip_bf16.h>
#include <math.h>
#include <cstddef>

namespace {

constexpr int kB   = 128;
constexpr int kS   = 256;
constexpr int kD   = 768;   // multiple of 32
constexpr int kSP  = 257;
constexpr int kN   = kB * kSP;   // 32896 = 257*128
constexpr int kARC = 500;
constexpr int kTAG = 100;
constexpr int KA   = 512;   // padded K for ARC features / T
constexpr int KT   = 128;   // padded K for TAG features

typedef __attribute__((ext_vector_type(8))) short short8;
typedef __attribute__((ext_vector_type(4))) float floatx4;

__device__ __forceinline__ float bfval(__hip_bfloat16 h) { return __bfloat162float(h); }
__device__ __forceinline__ float s2f(short s) {
  unsigned short us = (unsigned short)s;
  __hip_bfloat16 h;
  __builtin_memcpy(&h, &us, 2);
  return __bfloat162float(h);
}
__device__ __forceinline__ void splitf(float x, __hip_bfloat16* h, __hip_bfloat16* l) {
  __hip_bfloat16 hh = __float2bfloat16(x);
  *h = hh;
  *l = __float2bfloat16(x - __bfloat162float(hh));
}

// ---------- per-tensor dtype detection (1 = bf16 storage, 0 = fp32) ----------
__global__ void detect_dtype_n(const unsigned* __restrict__ raw, int* __restrict__ flag,
                               int nwords) {
  int lane = threadIdx.x;
  int ok = 0, nz = 0;
  if (lane < nwords) {
    unsigned w = raw[lane];
    if (w != 0u) {
      nz = 1;
      int e = (w >> 7) & 0xFF;
      ok = (e >= 90 && e <= 140);
    }
  }
  unsigned long long ball_ok = __ballot(ok);
  unsigned long long ball_nz = __ballot(nz);
  if (lane == 0) {
    int cok = __popcll(ball_ok), cnz = __popcll(ball_nz);
    flag[0] = (cok * 4 >= cnz * 3) ? 1 : 0;
  }
}

__device__ __forceinline__ float rawload(const void* p, size_t i, int bf) {
  return bf ? __bfloat162float(((const __hip_bfloat16*)p)[i]) : ((const float*)p)[i];
}

// fp32 canonicalize with element offset
__global__ void conv_off(const void* __restrict__ src, float* __restrict__ dst,
                         int n, long off, const int* __restrict__ flag) {
  int i = blockIdx.x * 256 + threadIdx.x;
  if (i >= n) return;
  dst[i] = rawload(src, (size_t)off + i, *flag);
}

// transpose + split weight: raw W[K][N] (row stride ldsrc) -> Wh/Wl [N][Kpad], zero pad
__global__ void wsplit_t(const void* __restrict__ src, const int* __restrict__ flag,
                         long srcOff, int ldsrc, int K, int N, int Kpad,
                         __hip_bfloat16* __restrict__ Wh, __hip_bfloat16* __restrict__ Wl) {
  long idx = (long)blockIdx.x * 256 + threadIdx.x;
  if (idx >= (long)N * Kpad) return;
  int n = (int)(idx / Kpad), k = (int)(idx % Kpad);
  float v = (k < K) ? rawload(src, (size_t)srcOff + (size_t)k * ldsrc + n, *flag) : 0.f;
  __hip_bfloat16 h, l;
  splitf(v, &h, &l);
  Wh[idx] = h; Wl[idx] = l;
}

// =================== split-bf16 MFMA GEMM (NT, both operands [rows][k]) ===================
// C[M,N] = act( sum_k (Ah+Al)[m,k]*(Bh+Bl)[n,k] + bias[n]? )  (drop lo*lo)
// EPI: 0 none, 1 bias+elu, 2 bias. Out: split planes Ch/Cl, ldc mult of 128; pads [N,ldc) zeroed.
constexpr int BM = 128, BN = 128, BK = 32, LDT = 40;

template <int EPI>
__global__ __launch_bounds__(256) void gemm_sp(
    const __hip_bfloat16* __restrict__ Ah, const __hip_bfloat16* __restrict__ Al, int lda,
    const __hip_bfloat16* __restrict__ Bh, const __hip_bfloat16* __restrict__ Bl, int ldb,
    __hip_bfloat16* __restrict__ Ch, __hip_bfloat16* __restrict__ Cl, int ldc,
    int M, int N, int K, const float* __restrict__ bias) {
  __shared__ __hip_bfloat16 sA[2][BM][LDT];
  __shared__ __hip_bfloat16 sB[2][BN][LDT];
  const int tid = threadIdx.x;
  const int lane = tid & 63, wave = tid >> 6;
  const int quad = lane >> 4, l15 = lane & 15;
  const int wm = (wave >> 1) * 64, wn = (wave & 1) * 64;
  const int m0 = blockIdx.x * BM, n0 = blockIdx.y * BN;
  const int srow = tid >> 2, sck = tid & 3;

  floatx4 acc[4][4] = {};
  for (int k0 = 0; k0 < K; k0 += BK) {
#pragma unroll
    for (int half = 0; half < 2; ++half) {
      int r = srow + half * 64;
      {
        int gm = m0 + r;
        short8 vh = {}, vl = {};
        if (gm < M) {
          vh = *(const short8*)(Ah + (size_t)gm * lda + k0 + sck * 8);
          vl = *(const short8*)(Al + (size_t)gm * lda + k0 + sck * 8);
        }
        *(short8*)&sA[0][r][sck * 8] = vh;
        *(short8*)&sA[1][r][sck * 8] = vl;
      }
      {
        int gn = n0 + r;
        short8 vh = {}, vl = {};
        if (gn < N) {
          vh = *(const short8*)(Bh + (size_t)gn * ldb + k0 + sck * 8);
          vl = *(const short8*)(Bl + (size_t)gn * ldb + k0 + sck * 8);
        }
        *(short8*)&sB[0][r][sck * 8] = vh;
        *(short8*)&sB[1][r][sck * 8] = vl;
      }
    }
    __syncthreads();
    short8 a_h[4], a_l[4], b_h[4], b_l[4];
#pragma unroll
    for (int t = 0; t < 4; ++t) {
      a_h[t] = *(const short8*)&sA[0][wm + t * 16 + l15][quad * 8];
      a_l[t] = *(const short8*)&sA[1][wm + t * 16 + l15][quad * 8];
      b_h[t] = *(const short8*)&sB[0][wn + t * 16 + l15][quad * 8];
      b_l[t] = *(const short8*)&sB[1][wn + t * 16 + l15][quad * 8];
    }
#pragma unroll
    for (int mt = 0; mt < 4; ++mt)
#pragma unroll
      for (int nt = 0; nt < 4; ++nt) {
        acc[mt][nt] = __builtin_amdgcn_mfma_f32_16x16x32_bf16(a_h[mt], b_h[nt], acc[mt][nt], 0, 0, 0);
        acc[mt][nt] = __builtin_amdgcn_mfma_f32_16x16x32_bf16(a_h[mt], b_l[nt], acc[mt][nt], 0, 0, 0);
        acc[mt][nt] = __builtin_amdgcn_mfma_f32_16x16x32_bf16(a_l[mt], b_h[nt], acc[mt][nt], 0, 0, 0);
      }
    __syncthreads();
  }
#pragma unroll
  for (int mt = 0; mt < 4; ++mt)
#pragma unroll
    for (int reg = 0; reg < 4; ++reg) {
      int m = m0 + wm + mt * 16 + quad * 4 + reg;
      if (m >= M) continue;
#pragma unroll
      for (int nt = 0; nt < 4; ++nt) {
        int n = n0 + wn + nt * 16 + l15;
        size_t o = (size_t)m * ldc + n;
        if (n < N) {
          float v = acc[mt][nt][reg];
          if (EPI >= 1) v += bias[n];
          if (EPI == 1) v = v > 0.f ? v : expm1f(v);
          __hip_bfloat16 h, l;
          splitf(v, &h, &l);
          Ch[o] = h; Cl[o] = l;
        } else if (n < ldc) {
          Ch[o] = __float2bfloat16(0.f);
          Cl[o] = __float2bfloat16(0.f);
        }
      }
    }
}

// ====== projection GEMM: A = virtual x (raw fp32/bf16), split on the fly; bias+elu; sp out ======
__global__ __launch_bounds__(256) void proj_sp(
    const void* __restrict__ inp, const void* __restrict__ sent,
    const int* __restrict__ flag_inp, const int* __restrict__ flag_sent,
    const __hip_bfloat16* __restrict__ Bh, const __hip_bfloat16* __restrict__ Bl,  // [N][768]
    __hip_bfloat16* __restrict__ Ch, __hip_bfloat16* __restrict__ Cl, int ldc,
    int M, int N, const float* __restrict__ bias, int g0) {
  __shared__ __hip_bfloat16 sA[2][BM][LDT];
  __shared__ __hip_bfloat16 sB[2][BN][LDT];
  const int bf_i = *flag_inp, bf_s = *flag_sent;
  const int tid = threadIdx.x;
  const int lane = tid & 63, wave = tid >> 6;
  const int quad = lane >> 4, l15 = lane & 15;
  const int wm = (wave >> 1) * 64, wn = (wave & 1) * 64;
  const int m0 = blockIdx.x * BM, n0 = blockIdx.y * BN;
  const int srow = tid >> 2, sck = tid & 3;

  floatx4 acc[4][4] = {};
  for (int k0 = 0; k0 < kD; k0 += BK) {
#pragma unroll
    for (int half = 0; half < 2; ++half) {
      int r = srow + half * 64;
      int gm = m0 + r;
      float v[8] = {0, 0, 0, 0, 0, 0, 0, 0};
      if (gm < M) {
        int b_loc = gm / kSP;
        int rr = gm - b_loc * kSP;
        int kk = k0 + sck * 8;
        if (rr == 0) {
          if (bf_s) {
            short8 s = *(const short8*)((const __hip_bfloat16*)sent + kk);
#pragma unroll
            for (int j = 0; j < 8; ++j) v[j] = s2f(s[j]);
          } else {
            floatx4 a = *(const floatx4*)((const float*)sent + kk);
            floatx4 b = *(const floatx4*)((const float*)sent + kk + 4);
#pragma unroll
            for (int j = 0; j < 4; ++j) { v[j] = a[j]; v[4 + j] = b[j]; }
          }
        } else {
          size_t base = ((size_t)((g0 + b_loc) * kS + (rr - 1))) * kD + kk;
          if (bf_i) {
            short8 s = *(const short8*)((const __hip_bfloat16*)inp + base);
#pragma unroll
            for (int j = 0; j < 8; ++j) v[j] = s2f(s[j]);
          } else {
            floatx4 a = *(const floatx4*)((const float*)inp + base);
            floatx4 b = *(const floatx4*)((const float*)inp + base + 4);
#pragma unroll
            for (int j = 0; j < 4; ++j) { v[j] = a[j]; v[4 + j] = b[j]; }
          }
        }
      }
#pragma unroll
      for (int j = 0; j < 8; ++j) {
        __hip_bfloat16 h, l;
        splitf(v[j], &h, &l);
        sA[0][r][sck * 8 + j] = h;
        sA[1][r][sck * 8 + j] = l;
      }
      {
        int gn = n0 + r;
        short8 vh = {}, vl = {};
        if (gn < N) {
          vh = *(const short8*)(Bh + (size_t)gn * kD + k0 + sck * 8);
          vl = *(const short8*)(Bl + (size_t)gn * kD + k0 + sck * 8);
        }
        *(short8*)&sB[0][r][sck * 8] = vh;
        *(short8*)&sB[1][r][sck * 8] = vl;
      }
    }
    __syncthreads();
    short8 a_h[4], a_l[4], b_h[4], b_l[4];
#pragma unroll
    for (int t = 0; t < 4; ++t) {
      a_h[t] = *(const short8*)&sA[0][wm + t * 16 + l15][quad * 8];
      a_l[t] = *(const short8*)&sA[1][wm + t * 16 + l15][quad * 8];
      b_h[t] = *(const short8*)&sB[0][wn + t * 16 + l15][quad * 8];
      b_l[t] = *(const short8*)&sB[1][wn + t * 16 + l15][quad * 8];
    }
#pragma unroll
    for (int mt = 0; mt < 4; ++mt)
#pragma unroll
      for (int nt = 0; nt < 4; ++nt) {
        acc[mt][nt] = __builtin_amdgcn_mfma_f32_16x16x32_bf16(a_h[mt], b_h[nt], acc[mt][nt], 0, 0, 0);
        acc[mt][nt] = __builtin_amdgcn_mfma_f32_16x16x32_bf16(a_h[mt], b_l[nt], acc[mt][nt], 0, 0, 0);
        acc[mt][nt] = __builtin_amdgcn_mfma_f32_16x16x32_bf16(a_l[mt], b_h[nt], acc[mt][nt], 0, 0, 0);
      }
    __syncthreads();
  }
#pragma unroll
  for (int mt = 0; mt < 4; ++mt)
#pragma unroll
    for (int reg = 0; reg < 4; ++reg) {
      int m = m0 + wm + mt * 16 + quad * 4 + reg;
      if (m >= M) continue;
#pragma unroll
      for (int nt = 0; nt < 4; ++nt) {
        int n = n0 + wn + nt * 16 + l15;
        size_t o = (size_t)m * ldc + n;
        if (n < N) {
          float v = acc[mt][nt][reg] + bias[n];
          v = v > 0.f ? v : expm1f(v);
          __hip_bfloat16 h, l;
          splitf(v, &h, &l);
          Ch[o] = h; Cl[o] = l;
        } else if (n < ldc) {
          Ch[o] = __float2bfloat16(0.f);
          Cl[o] = __float2bfloat16(0.f);
        }
      }
    }
}

// ====== batched NT bilinear: out fp32; +rowterm T[i][500] + bilb ======
__global__ __launch_bounds__(256) void bilnt_sp(
    const __hip_bfloat16* __restrict__ Th, const __hip_bfloat16* __restrict__ Tl,  // [GB*257][512]
    const __hip_bfloat16* __restrict__ Fh, const __hip_bfloat16* __restrict__ Fl,  // featDA
    float* __restrict__ out, const float* __restrict__ bilb, int bidx,
    int g0, int globOut) {
  __shared__ __hip_bfloat16 sA[2][BM][LDT];
  __shared__ __hip_bfloat16 sB[2][BN][LDT];
  const int z = blockIdx.z;
  const int tid = threadIdx.x;
  const int lane = tid & 63, wave = tid >> 6;
  const int quad = lane >> 4, l15 = lane & 15;
  const int wm = (wave >> 1) * 64, wn = (wave & 1) * 64;
  const int m0 = blockIdx.x * BM, n0 = blockIdx.y * BN;
  const int srow = tid >> 2, sck = tid & 3;
  const __hip_bfloat16* Ah = Th + (size_t)z * kSP * KA;
  const __hip_bfloat16* Al = Tl + (size_t)z * kSP * KA;
  const __hip_bfloat16* Bh = Fh + (size_t)z * kSP * KA;
  const __hip_bfloat16* Bl = Fl + (size_t)z * kSP * KA;

  floatx4 acc[4][4] = {};
  for (int k0 = 0; k0 < KA; k0 += BK) {
#pragma unroll
    for (int half = 0; half < 2; ++half) {
      int r = srow + half * 64;
      {
        int gm = m0 + r;
        short8 vh = {}, vl = {};
        if (gm < kSP) {
          vh = *(const short8*)(Ah + (size_t)gm * KA + k0 + sck * 8);
          vl = *(const short8*)(Al + (size_t)gm * KA + k0 + sck * 8);
        }
        *(short8*)&sA[0][r][sck * 8] = vh;
        *(short8*)&sA[1][r][sck * 8] = vl;
      }
      {
        int gn = n0 + r;
        short8 vh = {}, vl = {};
        if (gn < kSP) {
          vh = *(const short8*)(Bh + (size_t)gn * KA + k0 + sck * 8);
          vl = *(const short8*)(Bl + (size_t)gn * KA + k0 + sck * 8);
        }
        *(short8*)&sB[0][r][sck * 8] = vh;
        *(short8*)&sB[1][r][sck * 8] = vl;
      }
    }
    __syncthreads();
    short8 a_h[4], a_l[4], b_h[4], b_l[4];
#pragma unroll
    for (int t = 0; t < 4; ++t) {
      a_h[t] = *(const short8*)&sA[0][wm + t * 16 + l15][quad * 8];
      a_l[t] = *(const short8*)&sA[1][wm + t * 16 + l15][quad * 8];
      b_h[t] = *(const short8*)&sB[0][wn + t * 16 + l15][quad * 8];
      b_l[t] = *(const short8*)&sB[1][wn + t * 16 + l15][quad * 8];
    }
#pragma unroll
    for (int mt = 0; mt < 4; ++mt)
#pragma unroll
      for (int nt = 0; nt < 4; ++nt) {
        acc[mt][nt] = __builtin_amdgcn_mfma_f32_16x16x32_bf16(a_h[mt], b_h[nt], acc[mt][nt], 0, 0, 0);
        acc[mt][nt] = __builtin_amdgcn_mfma_f32_16x16x32_bf16(a_h[mt], b_l[nt], acc[mt][nt], 0, 0, 0);
        acc[mt][nt] = __builtin_amdgcn_mfma_f32_16x16x32_bf16(a_l[mt], b_h[nt], acc[mt][nt], 0, 0, 0);
      }
    __syncthreads();
  }
  const float sb = bilb[bidx];
  const int bb = globOut ? (g0 + z) : z;
#pragma unroll
  for (int mt = 0; mt < 4; ++mt)
#pragma unroll
    for (int reg = 0; reg < 4; ++reg) {
      int i = m0 + wm + mt * 16 + quad * 4 + reg;
      if (i >= kSP) continue;
      float rowterm = bfval(Ah[(size_t)i * KA + 500]) + bfval(Al[(size_t)i * KA + 500]) + sb;
#pragma unroll
      for (int nt = 0; nt < 4; ++nt) {
        int j = n0 + wn + nt * 16 + l15;
        if (j >= kSP) continue;
        out[((size_t)bb * kSP + i) * kSP + j] = acc[mt][nt][reg] + rowterm;
      }
    }
}

// ------------- per-row softmax + top-8 (+dinv); one wave per row -------------
__global__ void softmax_topk(const float* __restrict__ logits,
                             int* __restrict__ idx8,
                             float* __restrict__ val8,
                             float* __restrict__ dinv) {
  const int row = blockIdx.x;
  const int lane = threadIdx.x;
  const int rowbase = row - (row % kSP);
  const float* L = logits + (size_t)row * kSP;
  float v[5];
  int c[5];
#pragma unroll
  for (int q = 0; q < 5; ++q) {
    int j = lane + q * 64;
    c[q] = j;
    v[q] = (j < kSP) ? L[j] : -INFINITY;
  }
  float m = v[0];
#pragma unroll
  for (int q = 1; q < 5; ++q) m = fmaxf(m, v[q]);
  for (int off = 32; off > 0; off >>= 1) m = fmaxf(m, __shfl_xor(m, off));
  float s = 0.f;
#pragma unroll
  for (int q = 0; q < 5; ++q) s += expf(v[q] - m);
  for (int off = 32; off > 0; off >>= 1) s += __shfl_xor(s, off);
  const float invs = 1.f / s;
  float degsum = 0.f;
  for (int t = 0; t < 8; ++t) {
    float bvv = -INFINITY;
    int bii = kSP;
#pragma unroll
    for (int q = 0; q < 5; ++q)
      if (v[q] > bvv) { bvv = v[q]; bii = c[q]; }
    for (int off = 32; off > 0; off >>= 1) {
      float ov = __shfl_xor(bvv, off);
      int oi = __shfl_xor(bii, off);
      if (ov > bvv || (ov == bvv && oi < bii)) { bvv = ov; bii = oi; }
    }
    float p = expf(bvv - m) * invs;
    degsum += p;
    if (lane == 0) { idx8[row * 8 + t] = rowbase + bii; val8[row * 8 + t] = p; }
#pragma unroll
    for (int q = 0; q < 5; ++q)
      if (c[q] == bii) v[q] = -INFINITY;
  }
  if (lane == 0) dinv[row] = 1.f / sqrtf(1.f + degsum);
}

// ------------- GCN aggregation over split Y; out split (+pad zero) or fp32 -------------
template <int ELU, int OUTF32>
__global__ __launch_bounds__(256) void gcn_agg_sp(
    const __hip_bfloat16* __restrict__ Yh, const __hip_bfloat16* __restrict__ Yl, int ldy,
    int F,
    const int* __restrict__ idx8, const float* __restrict__ val8,
    const float* __restrict__ dinv,
    const float* __restrict__ bias,
    __hip_bfloat16* __restrict__ Zh, __hip_bfloat16* __restrict__ Zl,
    float* __restrict__ Zf, int ldzf) {
  const int n = blockIdx.x;
  __shared__ float w[9];
  __shared__ int srcs[8];
  const int t = threadIdx.x;
  if (t < 8) {
    int s = idx8[n * 8 + t];
    srcs[t] = s;
    w[t] = dinv[n] * val8[n * 8 + t] * dinv[s];
  } else if (t == 8) {
    float di = dinv[n];
    w[8] = di * di;
  }
  __syncthreads();
  const int lim = OUTF32 ? F : ldy;
  for (int f = t; f < lim; f += blockDim.x) {
    if (!OUTF32 && f >= F) {
      size_t o = (size_t)n * ldy + f;
      Zh[o] = __float2bfloat16(0.f);
      Zl[o] = __float2bfloat16(0.f);
      continue;
    }
    size_t off0 = (size_t)n * ldy + f;
    float acc = w[8] * (bfval(Yh[off0]) + bfval(Yl[off0]));
#pragma unroll
    for (int k = 0; k < 8; ++k) {
      size_t o = (size_t)srcs[k] * ldy + f;
      acc += w[k] * (bfval(Yh[o]) + bfval(Yl[o]));
    }
    acc += bias[f];
    if (ELU) acc = acc > 0.f ? acc : expm1f(acc);
    if (OUTF32) {
      Zf[(size_t)n * ldzf + f] = acc;
    } else {
      __hip_bfloat16 h, l;
      splitf(acc, &h, &l);
      size_t o = (size_t)n * ldy + f;
      Zh[o] = h; Zl[o] = l;
    }
  }
}

}  // namespace

extern "C" void kernel_launch(void* const* d_in, const int* in_sizes, int n_in,
                              void* d_out, int out_size, void* d_ws, size_t ws_size,
                              hipStream_t stream) {
  (void)out_size;

  // ---------- size-keyed role mapping ----------
  const int roleSize[20] = {kB * kS * kD, kD,
                            kD * kARC, kARC, kD * kARC, kARC,
                            kD * kTAG, kTAG, kD * kTAG, kTAG,
                            3 * 501 * 501, 3,
                            kARC * kARC, kARC, kARC * kARC, kARC,
                            kTAG * kTAG, kTAG, kTAG * kTAG, kTAG};
  const int roleOcc[20]  = {0, 0, 0, 0, 1, 1, 0, 0, 1, 1, 0, 0,
                            0, 2, 1, 3, 0, 2, 1, 3};
  int roleIdx[20] = {0, 5, 6, 7, 8, 9, 10, 11, 12, 13, 14, 15,
                     16, 17, 18, 19, 20, 21, 22, 23};
  for (int r = 0; r < 20; ++r) {
    int occ = 0, found = -1;
    for (int i = 0; i < n_in; ++i) {
      if (in_sizes[i] == roleSize[r]) {
        if (occ == roleOcc[r]) { found = i; break; }
        ++occ;
      }
    }
    if (found >= 0) roleIdx[r] = found;
    else if (roleIdx[r] >= n_in) roleIdx[r] = 0;
  }
  const void* src_of[20];
  for (int r = 0; r < 20; ++r) src_of[r] = d_in[roleIdx[r]];

  // ---- workspace layout (function of group batch count GB) ----
  auto need_bytes = [](int GB) -> size_t {
    size_t NG = (size_t)GB * kSP, s = 0;
    auto al = [&](size_t b) { s += (b + 255) & ~(size_t)255; };
    al(256);                                                  // flags
    for (int i = 0; i < 4; ++i) al((size_t)kARC * kD * 2);    // WtHA/DA h,l
    for (int i = 0; i < 4; ++i) al((size_t)kTAG * kD * 2);    // WtHT/DT h,l
    al(kARC * 4); al(kARC * 4); al(kTAG * 4); al(kTAG * 4);   // proj biases
    for (int i = 0; i < 6; ++i) al((size_t)501 * KA * 2);     // bilWt 3 x h,l
    al(3 * 501 * 4); al(256);                                 // brow, bilbf
    for (int i = 0; i < 4; ++i) al((size_t)kARC * KA * 2);    // c1a/c2a h,l
    for (int i = 0; i < 4; ++i) al((size_t)kTAG * KT * 2);    // c1r/c2r h,l
    al(kARC * 4); al(kARC * 4); al(kTAG * 4); al(kTAG * 4);   // conv biases
    for (int i = 0; i < 4; ++i) al(NG * KA * 2);              // fHA,fDA h,l
    for (int i = 0; i < 4; ++i) al(NG * KT * 2);              // fHT,fDT h,l
    for (int i = 0; i < 4; ++i) al(NG * KA * 2);              // Y,Z h,l
    al(NG * kSP * 4);                                         // logits
    al(NG * 8 * 4); al(NG * 8 * 4); al(NG * 4);               // edges
    return s;
  };
  int GB = 1;
  for (int cand : {128, 64, 32, 16, 8, 4, 2, 1})
    if (need_bytes(cand) <= ws_size) { GB = cand; break; }
  const int G = kB / GB;
  const int NG = GB * kSP;
  const int mb = (NG + BM - 1) / BM;

  char* ws = (char*)d_ws;
  size_t off = 0;
  auto alloc = [&](size_t bytes) -> void* {
    void* p = ws + off;
    off += (bytes + 255) & ~(size_t)255;
    return p;
  };
  typedef __hip_bfloat16 bf;
  int* flags = (int*)alloc(256);
  bf *WtHAh = (bf*)alloc((size_t)kARC * kD * 2), *WtHAl = (bf*)alloc((size_t)kARC * kD * 2);
  bf *WtDAh = (bf*)alloc((size_t)kARC * kD * 2), *WtDAl = (bf*)alloc((size_t)kARC * kD * 2);
  bf *WtHTh = (bf*)alloc((size_t)kTAG * kD * 2), *WtHTl = (bf*)alloc((size_t)kTAG * kD * 2);
  bf *WtDTh = (bf*)alloc((size_t)kTAG * kD * 2), *WtDTl = (bf*)alloc((size_t)kTAG * kD * 2);
  float* bha = (float*)alloc(kARC * 4);
  float* bda = (float*)alloc(kARC * 4);
  float* bht = (float*)alloc(kTAG * 4);
  float* bdt = (float*)alloc(kTAG * 4);
  bf* bilWh[3]; bf* bilWl[3];
  for (int k = 0; k < 3; ++k) {
    bilWh[k] = (bf*)alloc((size_t)501 * KA * 2);
    bilWl[k] = (bf*)alloc((size_t)501 * KA * 2);
  }
  float* brow = (float*)alloc(3 * 501 * 4);
  float* bilbf = (float*)alloc(256);
  bf *c1ah = (bf*)alloc((size_t)kARC * KA * 2), *c1al = (bf*)alloc((size_t)kARC * KA * 2);
  bf *c2ah = (bf*)alloc((size_t)kARC * KA * 2), *c2al = (bf*)alloc((size_t)kARC * KA * 2);
  bf *c1rh = (bf*)alloc((size_t)kTAG * KT * 2), *c1rl = (bf*)alloc((size_t)kTAG * KT * 2);
  bf *c2rh = (bf*)alloc((size_t)kTAG * KT * 2), *c2rl = (bf*)alloc((size_t)kTAG * KT * 2);
  float* c1ab = (float*)alloc(kARC * 4);
  float* c2ab = (float*)alloc(kARC * 4);
  float* c1rb = (float*)alloc(kTAG * 4);
  float* c2rb = (float*)alloc(kTAG * 4);
  bf *fHAh = (bf*)alloc((size_t)NG * KA * 2), *fHAl = (bf*)alloc((size_t)NG * KA * 2);
  bf *fDAh = (bf*)alloc((size_t)NG * KA * 2), *fDAl = (bf*)alloc((size_t)NG * KA * 2);
  bf *fHTh = (bf*)alloc((size_t)NG * KT * 2), *fHTl = (bf*)alloc((size_t)NG * KT * 2);
  bf *fDTh = (bf*)alloc((size_t)NG * KT * 2), *fDTl = (bf*)alloc((size_t)NG * KT * 2);
  bf *Yh = (bf*)alloc((size_t)NG * KA * 2), *Yl = (bf*)alloc((size_t)NG * KA * 2);
  bf *Zh = (bf*)alloc((size_t)NG * KA * 2), *Zl = (bf*)alloc((size_t)NG * KA * 2);
  float* logits = (float*)alloc((size_t)NG * kSP * 4);
  int*   idx8 = (int*)alloc((size_t)NG * 8 * 4);
  float* val8 = (float*)alloc((size_t)NG * 8 * 4);
  float* dinv = (float*)alloc((size_t)NG * 4);

  // ---- dtype flags ----
  for (int r = 0; r < 20; ++r) {
    int n = roleSize[r];
    int nwords = n / 4; if (nwords < 1) nwords = 1; if (nwords > 64) nwords = 64;
    detect_dtype_n<<<1, 64, 0, stream>>>((const unsigned*)src_of[r], flags + r, nwords);
  }
  // ---- fp32 biases ----
  auto cvt = [&](int role, float* dst, int n, long o) {
    conv_off<<<(n + 255) / 256, 256, 0, stream>>>(src_of[role], dst, n, o, flags + role);
  };
  cvt(3, bha, kARC, 0); cvt(5, bda, kARC, 0); cvt(7, bht, kTAG, 0); cvt(9, bdt, kTAG, 0);
  cvt(11, bilbf, 3, 0);
  cvt(13, c1ab, kARC, 0); cvt(15, c2ab, kARC, 0); cvt(17, c1rb, kTAG, 0); cvt(19, c2rb, kTAG, 0);
  // ---- transpose+split weights ----
  auto wsp = [&](int role, long o, int ldsrc, int K, int N, int Kpad, bf* Wh, bf* Wl) {
    long tot = (long)N * Kpad;
    wsplit_t<<<(int)((tot + 255) / 256), 256, 0, stream>>>(src_of[role], flags + role, o,
                                                           ldsrc, K, N, Kpad, Wh, Wl);
  };
  wsp(2, 0, kARC, kD, kARC, kD, WtHAh, WtHAl);
  wsp(4, 0, kARC, kD, kARC, kD, WtDAh, WtDAl);
  wsp(6, 0, kTAG, kD, kTAG, kD, WtHTh, WtHTl);
  wsp(8, 0, kTAG, kD, kTAG, kD, WtDTh, WtDTl);
  for (int k = 0; k < 3; ++k) {
    wsp(10, (long)k * 501 * 501, 501, 500, 501, KA, bilWh[k], bilWl[k]);
    cvt(10, brow + k * 501, 501, (long)k * 501 * 501 + 500 * 501);
  }
  wsp(12, 0, kARC, kARC, kARC, KA, c1ah, c1al);
  wsp(14, 0, kARC, kARC, kARC, KA, c2ah, c2al);
  wsp(16, 0, kTAG, kTAG, kTAG, KT, c1rh, c1rl);
  wsp(18, 0, kTAG, kTAG, kTAG, KT, c2rh, c2rl);

  float* outp = (float*)d_out;
  const size_t arc_elems = (size_t)kB * kSP * kSP;

  for (int g = 0; g < G; ++g) {
    const int g0 = g * GB;

    // projections (virtual x, split on the fly)
    proj_sp<<<dim3(mb, 4), 256, 0, stream>>>(src_of[0], src_of[1], flags + 0, flags + 1,
                                             WtHAh, WtHAl, fHAh, fHAl, KA, NG, kARC, bha, g0);
    proj_sp<<<dim3(mb, 4), 256, 0, stream>>>(src_of[0], src_of[1], flags + 0, flags + 1,
                                             WtDAh, WtDAl, fDAh, fDAl, KA, NG, kARC, bda, g0);
    proj_sp<<<dim3(mb, 1), 256, 0, stream>>>(src_of[0], src_of[1], flags + 0, flags + 1,
                                             WtHTh, WtHTl, fHTh, fHTl, KT, NG, kTAG, bht, g0);
    proj_sp<<<dim3(mb, 1), 256, 0, stream>>>(src_of[0], src_of[1], flags + 0, flags + 1,
                                             WtDTh, WtDTl, fDTh, fDTl, KT, NG, kTAG, bdt, g0);

    for (int k = 0; k < 2; ++k) {
      // T = [fHA|1] @ bilW_k  (N=501, bias = W row 500)
      gemm_sp<2><<<dim3(mb, 4), 256, 0, stream>>>(fHAh, fHAl, KA, bilWh[k], bilWl[k], KA,
                                                  Yh, Yl, KA, NG, 501, KA, brow + k * 501);
      bilnt_sp<<<dim3(3, 3, GB), 256, 0, stream>>>(Yh, Yl, fDAh, fDAl, logits, bilbf, k, g0, 0);
      softmax_topk<<<NG, 64, 0, stream>>>(logits, idx8, val8, dinv);

      // ARC features
      bf* fh[2] = {fHAh, fDAh};
      bf* fl[2] = {fHAl, fDAl};
      for (int ff = 0; ff < 2; ++ff) {
        gemm_sp<0><<<dim3(mb, 4), 256, 0, stream>>>(fh[ff], fl[ff], KA, c1ah, c1al, KA,
                                                    Yh, Yl, KA, NG, kARC, KA, nullptr);
        gcn_agg_sp<1, 0><<<NG, 256, 0, stream>>>(Yh, Yl, KA, kARC, idx8, val8, dinv, c1ab,
                                                 Zh, Zl, nullptr, 0);
        gemm_sp<0><<<dim3(mb, 4), 256, 0, stream>>>(Zh, Zl, KA, c2ah, c2al, KA,
                                                    Yh, Yl, KA, NG, kARC, KA, nullptr);
        gcn_agg_sp<0, 0><<<NG, 256, 0, stream>>>(Yh, Yl, KA, kARC, idx8, val8, dinv, c2ab,
                                                 fh[ff], fl[ff], nullptr, 0);
      }
      // TAG features
      bf* th[2] = {fHTh, fDTh};
      bf* tl[2] = {fHTl, fDTl};
      for (int ff = 0; ff < 2; ++ff) {
        gemm_sp<0><<<dim3(mb, 1), 256, 0, stream>>>(th[ff], tl[ff], KT, c1rh, c1rl, KT,
                                                    Zh, Zl, KT, NG, kTAG, KT, nullptr);
        gcn_agg_sp<1, 0><<<NG, 256, 0, stream>>>(Zh, Zl, KT, kTAG, idx8, val8, dinv, c1rb,
                                                 Yh, Yl, nullptr, 0);
        gemm_sp<0><<<dim3(mb, 1), 256, 0, stream>>>(Yh, Yl, KT, c2rh, c2rl, KT,
                                                    Zh, Zl, KT, NG, kTAG, KT, nullptr);
        if (k == 1) {
          // final tag output -> d_out fp32
          float* dst = outp + arc_elems + (ff == 1 ? (size_t)kN * kTAG : 0)
                       + (size_t)g0 * kSP * kTAG;
          gcn_agg_sp<0, 1><<<NG, 256, 0, stream>>>(Zh, Zl, KT, kTAG, idx8, val8, dinv, c2rb,
                                                   nullptr, nullptr, dst, kTAG);
        } else {
          gcn_agg_sp<0, 0><<<NG, 256, 0, stream>>>(Zh, Zl, KT, kTAG, idx8, val8, dinv, c2rb,
                                                   th[ff], tl[ff], nullptr, 0);
        }
      }
    }

    // final bilinear -> d_out fp32
    gemm_sp<2><<<dim3(mb, 4), 256, 0, stream>>>(fHAh, fHAl, KA, bilWh[2], bilWl[2], KA,
                                                Yh, Yl, KA, NG, 501, KA, brow + 2 * 501);
    bilnt_sp<<<dim3(3, 3, GB), 256, 0, stream>>>(Yh, Yl, fDAh, fDAl, outp, bilbf, 2, g0, 1);
  }
}